// Round 1
// baseline (547.077 us; speedup 1.0000x reference)
//
#include <hip/hip_runtime.h>

// Event-warp + bilinear splat.
// Inputs (setup_inputs order):
//   d_in[0] flow  : float32 [B,2,H,W]   (ch0 = x-flow, ch1 = y-flow)
//   d_in[1] ts    : float32 [B,N,1]
//   d_in[2] ev_y  : int32   [B,N]
//   d_in[3] ev_x  : int32   [B,N]
//   d_in[4] pol   : int32   [B,N]  (1 = pos, 0 = neg)
// Output: float32 [B,4,H,W] = (iwe_pos, iwe_neg, iwe_pos_ts, iwe_neg_ts)

#define IMG_H 480
#define IMG_W 640

__global__ void __launch_bounds__(256)
event_splat_kernel(const float* __restrict__ flow,
                   const float* __restrict__ ts,
                   const int*   __restrict__ ev_y,
                   const int*   __restrict__ ev_x,
                   const int*   __restrict__ pol,
                   float*       __restrict__ out,
                   int B, int N) {
    const int i = blockIdx.x * blockDim.x + threadIdx.x;
    const int total = B * N;
    if (i >= total) return;

    const int b = i / N;

    const int   y = ev_y[i];
    const int   x = ev_x[i];
    const float t = ts[i];
    const int   p = pol[i];

    // Events sit on integer pixels -> bilinear gather of flow collapses to a
    // direct lookup (corner (0,0) weight is exactly 1, others 0).
    const float* fb = flow + (size_t)b * 2 * IMG_H * IMG_W;
    const int pix = y * IMG_W + x;
    const float fx = fb[pix];                     // channel 0 = x-flow
    const float fy = fb[IMG_H * IMG_W + pix];     // channel 1 = y-flow

    const float dt = 1.0f - t;                    // TREF - ts
    const float wy = (float)y + dt * fy;
    const float wx = (float)x + dt * fx;

    const float by = floorf(wy);
    const float bx = floorf(wx);
    const float ay = wy - by;                     // in [0,1)
    const float ax = wx - bx;
    const int iy0 = (int)by;
    const int ix0 = (int)bx;

    // bilinear corner weights: (1-ay,ay) x (1-ax,ax)
    const float wyv[2] = {1.0f - ay, ay};
    const float wxv[2] = {1.0f - ax, ax};

    const float norm_ts = 1.0f - fabsf(1.0f - t);  // == t for ts in [0,1]

    const int plane_c = p ? 0 : 1;   // count plane
    const int plane_t = p ? 2 : 3;   // ts plane
    float* out_c = out + ((size_t)b * 4 + plane_c) * IMG_H * IMG_W;
    float* out_t = out + ((size_t)b * 4 + plane_t) * IMG_H * IMG_W;

    #pragma unroll
    for (int dy = 0; dy < 2; ++dy) {
        const int iy = iy0 + dy;
        if (iy < 0 || iy > IMG_H - 1) continue;
        #pragma unroll
        for (int dx = 0; dx < 2; ++dx) {
            const int ix = ix0 + dx;
            if (ix < 0 || ix > IMG_W - 1) continue;
            const float w = wyv[dy] * wxv[dx];
            const int o = iy * IMG_W + ix;
            atomicAdd(out_c + o, w);
            atomicAdd(out_t + o, w * norm_ts);
        }
    }
}

extern "C" void kernel_launch(void* const* d_in, const int* in_sizes, int n_in,
                              void* d_out, int out_size, void* d_ws, size_t ws_size,
                              hipStream_t stream) {
    const float* flow = (const float*)d_in[0];
    const float* ts   = (const float*)d_in[1];
    const int*   ev_y = (const int*)d_in[2];
    const int*   ev_x = (const int*)d_in[3];
    const int*   pol  = (const int*)d_in[4];
    float* out = (float*)d_out;

    const int BN = in_sizes[2];                 // B*N
    const int B  = out_size / (4 * IMG_H * IMG_W);
    const int N  = BN / B;

    // d_out is poisoned with 0xAA before every timed launch — zero it.
    hipMemsetAsync(d_out, 0, (size_t)out_size * sizeof(float), stream);

    const int threads = 256;
    const int blocks = (BN + threads - 1) / threads;
    event_splat_kernel<<<blocks, threads, 0, stream>>>(flow, ts, ev_y, ev_x, pol,
                                                       out, B, N);
}

// Round 2
// 227.628 us; speedup vs baseline: 2.4034x; 2.4034x over previous
//
#include <hip/hip_runtime.h>

// Event-warp + bilinear splat via counting sort + LDS tile accumulation.
// Inputs (setup_inputs order):
//   d_in[0] flow  : float32 [B,2,H,W]   (ch0 = x-flow, ch1 = y-flow)
//   d_in[1] ts    : float32 [B,N,1]
//   d_in[2] ev_y  : int32   [B,N]
//   d_in[3] ev_x  : int32   [B,N]
//   d_in[4] pol   : int32   [B,N]  (1 = pos, 0 = neg)
// Output: float32 [B,4,H,W] = (iwe_pos, iwe_neg, iwe_pos_ts, iwe_neg_ts)

#define IMG_H 480
#define IMG_W 640
#define TILE_H 32
#define TILE_W 64
#define TILES_Y (IMG_H / TILE_H)   // 15
#define TILES_X (IMG_W / TILE_W)   // 10
#define TILES_PER_B (TILES_Y * TILES_X)  // 150
#define NTILES 600                 // B=4 * 150 (fallback used otherwise)

#define ACC_H (TILE_H + 1)         // 33
#define ACC_W (TILE_W + 1)         // 65
#define ACC_PLANE (ACC_H * ACC_W)  // 2145
#define ACC_SZ (4 * ACC_PLANE)     // 8580 floats = 34,320 B LDS

// ws layout (byte offsets)
#define WS_HIST 0                  // 600 * u32
#define WS_OFFS 4096               // 601 * u32
#define WS_CURS 8192               // 600 * u32
#define WS_RECS 16384              // total * 16B float4 records

#define SENTINEL 0xFFFFFFFFu

// ---------------------------------------------------------------------------
// Shared per-event computation: warp the event, find its destination tile.
// Must be bit-identical between hist and scatter passes (it is: same code).
__device__ __forceinline__ unsigned
compute_tile(const float* __restrict__ flow, const float* __restrict__ ts,
             const int* __restrict__ ev_y, const int* __restrict__ ev_x,
             const int* __restrict__ pol, int i, int N,
             float& wy, float& wx, float& nts, int& p) {
    const int b = i / N;
    const int y = ev_y[i];
    const int x = ev_x[i];
    const float t = ts[i];
    p = pol[i];
    // events sit on integer pixels -> flow bilinear gather degenerates to lookup
    const float* fb = flow + (size_t)b * 2 * IMG_H * IMG_W;
    const int pix = y * IMG_W + x;
    const float fx = fb[pix];                  // ch0 = x-flow
    const float fy = fb[IMG_H * IMG_W + pix];  // ch1 = y-flow
    const float dt = 1.0f - t;                 // TREF - ts
    wy = (float)y + dt * fy;
    wx = (float)x + dt * fx;
    nts = 1.0f - fabsf(1.0f - t);
    const int iy0 = (int)floorf(wy);
    const int ix0 = (int)floorf(wx);
    // event contributes iff at least one bilinear corner is in-image
    if (iy0 < -1 || iy0 > IMG_H - 1 || ix0 < -1 || ix0 > IMG_W - 1)
        return SENTINEL;
    const int cy = min(max(iy0, 0), IMG_H - 1);
    const int cx = min(max(ix0, 0), IMG_W - 1);
    const int ty = cy / TILE_H;
    const int tx = cx / TILE_W;
    return (unsigned)((b * TILES_Y + ty) * TILES_X + tx);
}

// ---------------------------------------------------------------------------
// Pass 1: per-tile histogram (LDS-aggregated)
__global__ void __launch_bounds__(256)
hist_kernel(const float* __restrict__ flow, const float* __restrict__ ts,
            const int* __restrict__ ev_y, const int* __restrict__ ev_x,
            const int* __restrict__ pol,
            unsigned* __restrict__ hist, int N, int total) {
    __shared__ unsigned lhist[NTILES];
    const int tid = threadIdx.x;
    for (int j = tid; j < NTILES; j += 256) lhist[j] = 0;
    __syncthreads();
    const int stride = gridDim.x * 256;
    for (int i = blockIdx.x * 256 + tid; i < total; i += stride) {
        float wy, wx, nts; int p;
        unsigned tile = compute_tile(flow, ts, ev_y, ev_x, pol, i, N, wy, wx, nts, p);
        if (tile != SENTINEL) atomicAdd(&lhist[tile], 1u);
    }
    __syncthreads();
    for (int j = tid; j < NTILES; j += 256) {
        unsigned n = lhist[j];
        if (n) atomicAdd(&hist[j], n);
    }
}

// ---------------------------------------------------------------------------
// Pass 2: exclusive prefix sum over 600 tile counts (single block)
__global__ void __launch_bounds__(1024)
scan_kernel(const unsigned* __restrict__ hist, unsigned* __restrict__ offs,
            unsigned* __restrict__ curs) {
    __shared__ unsigned s[1024];
    const int t = threadIdx.x;
    s[t] = (t < NTILES) ? hist[t] : 0u;
    __syncthreads();
    #pragma unroll
    for (int d = 1; d < 1024; d <<= 1) {
        unsigned v = (t >= d) ? s[t - d] : 0u;
        __syncthreads();
        s[t] += v;
        __syncthreads();
    }
    if (t < NTILES) {
        unsigned excl = (t == 0) ? 0u : s[t - 1];
        offs[t] = excl;
        curs[t] = excl;
        if (t == NTILES - 1) offs[NTILES] = s[t];
    }
}

// ---------------------------------------------------------------------------
// Pass 3: scatter events into tile-sorted record array.
// Block-aggregated cursor reservation: one global atomic per (block, tile).
#define SC_IPT 8
#define SC_CHUNK (256 * SC_IPT)   // 2048 events per block
__global__ void __launch_bounds__(256)
scatter_kernel(const float* __restrict__ flow, const float* __restrict__ ts,
               const int* __restrict__ ev_y, const int* __restrict__ ev_x,
               const int* __restrict__ pol,
               unsigned* __restrict__ curs, float4* __restrict__ recs,
               int N, int total) {
    __shared__ unsigned lhist[NTILES];
    __shared__ unsigned lbase[NTILES];
    const int tid = threadIdx.x;
    for (int j = tid; j < NTILES; j += 256) lhist[j] = 0;
    __syncthreads();

    const int base_i = blockIdx.x * SC_CHUNK;
    unsigned tK[SC_IPT], rkK[SC_IPT];
    float wyK[SC_IPT], wxK[SC_IPT], ntsK[SC_IPT];
    int pK[SC_IPT];
    #pragma unroll
    for (int k = 0; k < SC_IPT; ++k) {
        const int i = base_i + k * 256 + tid;
        unsigned tile = SENTINEL;
        if (i < total)
            tile = compute_tile(flow, ts, ev_y, ev_x, pol, i, N,
                                wyK[k], wxK[k], ntsK[k], pK[k]);
        tK[k] = tile;
        if (tile != SENTINEL) rkK[k] = atomicAdd(&lhist[tile], 1u);
    }
    __syncthreads();
    for (int j = tid; j < NTILES; j += 256) {
        unsigned n = lhist[j];
        lbase[j] = n ? atomicAdd(&curs[j], n) : 0u;
    }
    __syncthreads();
    #pragma unroll
    for (int k = 0; k < SC_IPT; ++k) {
        const unsigned tile = tK[k];
        if (tile != SENTINEL) {
            const unsigned slot = lbase[tile] + rkK[k];
            float4 r;
            r.x = wyK[k]; r.y = wxK[k]; r.z = ntsK[k];
            r.w = __uint_as_float((tile << 1) | (unsigned)(pK[k] & 1));
            recs[slot] = r;
        }
    }
}

// ---------------------------------------------------------------------------
// Pass 4: per-tile LDS accumulation + writeout.
// Interior cells: plain store. Cells on shared tile boundaries: atomicAdd.
__global__ void __launch_bounds__(256)
splat_kernel(const float4* __restrict__ recs, const unsigned* __restrict__ offs,
             float* __restrict__ out) {
    __shared__ float acc[ACC_SZ];   // [4 planes][33][65]
    const int tile = blockIdx.x;
    const int tid = threadIdx.x;
    for (int j = tid; j < ACC_SZ; j += 256) acc[j] = 0.0f;
    __syncthreads();

    const int b  = tile / TILES_PER_B;
    const int rb = tile % TILES_PER_B;
    const int ty = rb / TILES_X;
    const int tx = rb % TILES_X;
    const int y0 = ty * TILE_H;
    const int x0 = tx * TILE_W;

    const unsigned start = offs[tile];
    const unsigned end   = offs[tile + 1];
    for (unsigned i = start + tid; i < end; i += 256) {
        const float4 r = recs[i];
        const float wy = r.x, wx = r.y, nts = r.z;
        const int p = (int)(__float_as_uint(r.w) & 1u);
        const float byf = floorf(wy), bxf = floorf(wx);
        const int iy0 = (int)byf, ix0 = (int)bxf;
        const float ay = wy - byf, ax = wx - bxf;
        const float wyv[2] = {1.0f - ay, ay};
        const float wxv[2] = {1.0f - ax, ax};
        const int pc = p ? 0 : 1;   // count plane
        float* accc = acc + pc * ACC_PLANE;
        float* acct = accc + 2 * ACC_PLANE;   // ts plane
        #pragma unroll
        for (int dy = 0; dy < 2; ++dy) {
            const int gy = iy0 + dy;
            if (gy < 0 || gy >= IMG_H) continue;
            const int rr = gy - y0;           // in [0, TILE_H]
            #pragma unroll
            for (int dx = 0; dx < 2; ++dx) {
                const int gx = ix0 + dx;
                if (gx < 0 || gx >= IMG_W) continue;
                const int cc = gx - x0;       // in [0, TILE_W]
                const float w = wyv[dy] * wxv[dx];
                const int idx = rr * ACC_W + cc;
                atomicAdd(&accc[idx], w);
                atomicAdd(&acct[idx], w * nts);
            }
        }
    }
    __syncthreads();

    float* outb = out + (size_t)b * 4 * IMG_H * IMG_W;
    for (int j = tid; j < ACC_SZ; j += 256) {
        const int plane = j / ACC_PLANE;
        const int rem = j % ACC_PLANE;
        const int rr = rem / ACC_W;
        const int cc = rem % ACC_W;
        const int gy = y0 + rr;
        const int gx = x0 + cc;
        if (gy >= IMG_H || gx >= IMG_W) continue;
        const float v = acc[j];
        const bool shared_cell = (rr == 0 && ty > 0) || (rr == TILE_H) ||
                                 (cc == 0 && tx > 0) || (cc == TILE_W);
        float* dst = outb + (size_t)plane * IMG_H * IMG_W + gy * IMG_W + gx;
        if (shared_cell) {
            if (v != 0.0f) atomicAdd(dst, v);
        } else {
            *dst = v;
        }
    }
}

// ---------------------------------------------------------------------------
// Fallback (round-1 style): direct global atomics. Used if ws too small / B!=4.
__global__ void __launch_bounds__(256)
event_splat_fallback(const float* __restrict__ flow, const float* __restrict__ ts,
                     const int* __restrict__ ev_y, const int* __restrict__ ev_x,
                     const int* __restrict__ pol, float* __restrict__ out,
                     int N, int total) {
    const int i = blockIdx.x * blockDim.x + threadIdx.x;
    if (i >= total) return;
    float wy, wx, nts; int p;
    unsigned tile = compute_tile(flow, ts, ev_y, ev_x, pol, i, N, wy, wx, nts, p);
    if (tile == SENTINEL) return;
    const int b = i / N;
    const float byf = floorf(wy), bxf = floorf(wx);
    const int iy0 = (int)byf, ix0 = (int)bxf;
    const float ay = wy - byf, ax = wx - bxf;
    const float wyv[2] = {1.0f - ay, ay};
    const float wxv[2] = {1.0f - ax, ax};
    float* out_c = out + ((size_t)b * 4 + (p ? 0 : 1)) * IMG_H * IMG_W;
    float* out_t = out_c + 2 * IMG_H * IMG_W;
    #pragma unroll
    for (int dy = 0; dy < 2; ++dy) {
        const int gy = iy0 + dy;
        if (gy < 0 || gy >= IMG_H) continue;
        #pragma unroll
        for (int dx = 0; dx < 2; ++dx) {
            const int gx = ix0 + dx;
            if (gx < 0 || gx >= IMG_W) continue;
            const float w = wyv[dy] * wxv[dx];
            const int o = gy * IMG_W + gx;
            atomicAdd(out_c + o, w);
            atomicAdd(out_t + o, w * nts);
        }
    }
}

// ---------------------------------------------------------------------------
extern "C" void kernel_launch(void* const* d_in, const int* in_sizes, int n_in,
                              void* d_out, int out_size, void* d_ws, size_t ws_size,
                              hipStream_t stream) {
    const float* flow = (const float*)d_in[0];
    const float* ts   = (const float*)d_in[1];
    const int*   ev_y = (const int*)d_in[2];
    const int*   ev_x = (const int*)d_in[3];
    const int*   pol  = (const int*)d_in[4];
    float* out = (float*)d_out;

    const int total = in_sizes[2];                  // B*N
    const int B = out_size / (4 * IMG_H * IMG_W);
    const int N = total / B;

    // d_out is poisoned with 0xAA before every timed launch — zero it.
    hipMemsetAsync(d_out, 0, (size_t)out_size * sizeof(float), stream);

    const size_t ws_needed = (size_t)WS_RECS + (size_t)total * sizeof(float4);
    if (B * TILES_PER_B != NTILES || ws_size < ws_needed) {
        // fallback: direct-atomic kernel
        const int blocks = (total + 255) / 256;
        event_splat_fallback<<<blocks, 256, 0, stream>>>(flow, ts, ev_y, ev_x, pol,
                                                         out, N, total);
        return;
    }

    char* ws = (char*)d_ws;
    unsigned* hist = (unsigned*)(ws + WS_HIST);
    unsigned* offs = (unsigned*)(ws + WS_OFFS);
    unsigned* curs = (unsigned*)(ws + WS_CURS);
    float4*   recs = (float4*)(ws + WS_RECS);

    hipMemsetAsync(hist, 0, NTILES * sizeof(unsigned), stream);

    hist_kernel<<<150, 256, 0, stream>>>(flow, ts, ev_y, ev_x, pol, hist, N, total);
    scan_kernel<<<1, 1024, 0, stream>>>(hist, offs, curs);
    const int sc_blocks = (total + SC_CHUNK - 1) / SC_CHUNK;
    scatter_kernel<<<sc_blocks, 256, 0, stream>>>(flow, ts, ev_y, ev_x, pol,
                                                  curs, recs, N, total);
    splat_kernel<<<NTILES, 256, 0, stream>>>(recs, offs, out);
}

// Round 3
// 209.468 us; speedup vs baseline: 2.6117x; 1.0867x over previous
//
#include <hip/hip_runtime.h>

// Event-warp + bilinear splat: coarse counting-sort (600 buckets) +
// ownership-tile LDS splat (2400 blocks, atomic-free writeout).
// Inputs (setup_inputs order):
//   d_in[0] flow  : float32 [B,2,H,W]   (ch0 = x-flow, ch1 = y-flow)
//   d_in[1] ts    : float32 [B,N,1]
//   d_in[2] ev_y  : int32   [B,N]
//   d_in[3] ev_x  : int32   [B,N]
//   d_in[4] pol   : int32   [B,N]  (1 = pos, 0 = neg)
// Output: float32 [B,4,H,W] = (iwe_pos, iwe_neg, iwe_pos_ts, iwe_neg_ts)

#define IMG_H 480
#define IMG_W 640

// Coarse sort buckets: 32x64
#define CB_H 32
#define CB_W 64
#define CBY (IMG_H / CB_H)        // 15
#define CBX (IMG_W / CB_W)        // 10
#define CB_PER_B (CBY * CBX)      // 150
#define NCB 600                   // B=4 * 150

// Ownership (splat) tiles: 16x32
#define OT_H 16
#define OT_W 32
#define OTY (IMG_H / OT_H)        // 30
#define OTX (IMG_W / OT_W)        // 20
#define OT_PER_B (OTY * OTX)      // 600

#define ACC_PLANE (OT_H * OT_W)   // 512 floats
#define ACC_TOT (4 * ACC_PLANE)   // 2048 floats = 8 KB LDS

// ws layout (byte offsets)
#define WS_HIST 0                 // NCB * u32
#define WS_OFFS 4096              // (NCB+1) * u32
#define WS_CURS 8192              // NCB * u32
#define WS_RECS 16384             // total * 16B float4 records

#define SENTINEL 0xFFFFFFFFu

// ---------------------------------------------------------------------------
// Warp one event, return its coarse bucket (by clamped top-left corner).
// Buckets only spill DOWN/RIGHT by one pixel: in-image corners of a bucket-T
// record lie in rows [32*Ty, 32*Ty+32], cols [64*Tx, 64*Tx+64].
__device__ __forceinline__ unsigned
compute_tile(const float* __restrict__ flow, const float* __restrict__ ts,
             const int* __restrict__ ev_y, const int* __restrict__ ev_x,
             const int* __restrict__ pol, int i, int N,
             float& wy, float& wx, float& nts, int& p) {
    const int b = i / N;
    const int y = ev_y[i];
    const int x = ev_x[i];
    const float t = ts[i];
    p = pol[i];
    const float* fb = flow + (size_t)b * 2 * IMG_H * IMG_W;
    const int pix = y * IMG_W + x;
    const float fx = fb[pix];                  // ch0 = x-flow
    const float fy = fb[IMG_H * IMG_W + pix];  // ch1 = y-flow
    const float dt = 1.0f - t;                 // TREF - ts
    wy = (float)y + dt * fy;
    wx = (float)x + dt * fx;
    nts = 1.0f - fabsf(1.0f - t);
    const int iy0 = (int)floorf(wy);
    const int ix0 = (int)floorf(wx);
    if (iy0 < -1 || iy0 > IMG_H - 1 || ix0 < -1 || ix0 > IMG_W - 1)
        return SENTINEL;
    const int cy = min(max(iy0, 0), IMG_H - 1);
    const int cx = min(max(ix0, 0), IMG_W - 1);
    return (unsigned)((b * CBY + cy / CB_H) * CBX + cx / CB_W);
}

// ---------------------------------------------------------------------------
// Pass 1: per-bucket histogram. 300 blocks, 4-way ILP batch per iteration.
__global__ void __launch_bounds__(256)
hist_kernel(const float* __restrict__ flow, const float* __restrict__ ts,
            const int* __restrict__ ev_y, const int* __restrict__ ev_x,
            const int* __restrict__ pol,
            unsigned* __restrict__ hist, int N, int total) {
    __shared__ unsigned lh[NCB];
    const int tid = threadIdx.x;
    for (int j = tid; j < NCB; j += 256) lh[j] = 0;
    __syncthreads();
    const int stride = gridDim.x * 256;
    for (int i = blockIdx.x * 256 + tid; i < total; i += 4 * stride) {
        unsigned t0 = SENTINEL, t1 = SENTINEL, t2 = SENTINEL, t3 = SENTINEL;
        float wy, wx, nts; int p;
        t0 = compute_tile(flow, ts, ev_y, ev_x, pol, i, N, wy, wx, nts, p);
        if (i + stride < total)
            t1 = compute_tile(flow, ts, ev_y, ev_x, pol, i + stride, N, wy, wx, nts, p);
        if (i + 2 * stride < total)
            t2 = compute_tile(flow, ts, ev_y, ev_x, pol, i + 2 * stride, N, wy, wx, nts, p);
        if (i + 3 * stride < total)
            t3 = compute_tile(flow, ts, ev_y, ev_x, pol, i + 3 * stride, N, wy, wx, nts, p);
        if (t0 != SENTINEL) atomicAdd(&lh[t0], 1u);
        if (t1 != SENTINEL) atomicAdd(&lh[t1], 1u);
        if (t2 != SENTINEL) atomicAdd(&lh[t2], 1u);
        if (t3 != SENTINEL) atomicAdd(&lh[t3], 1u);
    }
    __syncthreads();
    for (int j = tid; j < NCB; j += 256) {
        unsigned n = lh[j];
        if (n) atomicAdd(&hist[j], n);
    }
}

// ---------------------------------------------------------------------------
// Pass 2: exclusive prefix sum over NCB bucket counts (single block)
__global__ void __launch_bounds__(1024)
scan_kernel(const unsigned* __restrict__ hist, unsigned* __restrict__ offs,
            unsigned* __restrict__ curs) {
    __shared__ unsigned s[1024];
    const int t = threadIdx.x;
    s[t] = (t < NCB) ? hist[t] : 0u;
    __syncthreads();
    #pragma unroll
    for (int d = 1; d < 1024; d <<= 1) {
        unsigned v = (t >= d) ? s[t - d] : 0u;
        __syncthreads();
        s[t] += v;
        __syncthreads();
    }
    if (t < NCB) {
        unsigned excl = (t == 0) ? 0u : s[t - 1];
        offs[t] = excl;
        curs[t] = excl;
        if (t == NCB - 1) offs[NCB] = s[t];
    }
}

// ---------------------------------------------------------------------------
// Pass 3: scatter events into bucket-sorted record array.
#define SC_IPT 8
#define SC_CHUNK (256 * SC_IPT)   // 2048 events per block
__global__ void __launch_bounds__(256)
scatter_kernel(const float* __restrict__ flow, const float* __restrict__ ts,
               const int* __restrict__ ev_y, const int* __restrict__ ev_x,
               const int* __restrict__ pol,
               unsigned* __restrict__ curs, float4* __restrict__ recs,
               int N, int total) {
    __shared__ unsigned lhist[NCB];
    __shared__ unsigned lbase[NCB];
    const int tid = threadIdx.x;
    for (int j = tid; j < NCB; j += 256) lhist[j] = 0;
    __syncthreads();

    const int base_i = blockIdx.x * SC_CHUNK;
    unsigned tK[SC_IPT], rkK[SC_IPT];
    float wyK[SC_IPT], wxK[SC_IPT], ntsK[SC_IPT];
    int pK[SC_IPT];
    #pragma unroll
    for (int k = 0; k < SC_IPT; ++k) {
        const int i = base_i + k * 256 + tid;
        unsigned tile = SENTINEL;
        if (i < total)
            tile = compute_tile(flow, ts, ev_y, ev_x, pol, i, N,
                                wyK[k], wxK[k], ntsK[k], pK[k]);
        tK[k] = tile;
        if (tile != SENTINEL) rkK[k] = atomicAdd(&lhist[tile], 1u);
    }
    __syncthreads();
    for (int j = tid; j < NCB; j += 256) {
        unsigned n = lhist[j];
        lbase[j] = n ? atomicAdd(&curs[j], n) : 0u;
    }
    __syncthreads();
    #pragma unroll
    for (int k = 0; k < SC_IPT; ++k) {
        const unsigned tile = tK[k];
        if (tile != SENTINEL) {
            const unsigned slot = lbase[tile] + rkK[k];
            float4 r;
            r.x = wyK[k]; r.y = wxK[k]; r.z = ntsK[k];
            r.w = __uint_as_float((unsigned)(pK[k] & 1));
            recs[slot] = r;
        }
    }
}

// ---------------------------------------------------------------------------
// Pass 4: one block per 16x32 ownership tile. Reads the 1-4 coarse buckets
// that can splat into this tile; accepts a corner iff this tile owns that
// pixel (test also rejects out-of-image corners). Writeout: pure float4
// stores (exclusive ownership) — no atomics, no out-memset needed.
__global__ void __launch_bounds__(256)
splat_kernel(const float4* __restrict__ recs, const unsigned* __restrict__ offs,
             float* __restrict__ out) {
    __shared__ __align__(16) float acc[ACC_TOT];   // [4 planes][16][32]
    const int tile = blockIdx.x;
    const int tid = threadIdx.x;
    #pragma unroll
    for (int j = tid; j < ACC_TOT; j += 256) acc[j] = 0.0f;
    __syncthreads();

    const int b  = tile / OT_PER_B;
    const int rb = tile % OT_PER_B;
    const int sy = rb / OTX;                  // own tile row   [0,30)
    const int sx = rb % OTX;                  // own tile col   [0,20)

    // coarse buckets whose spill range intersects this ownership tile
    const int ty_hi = sy >> 1;
    const int tx_hi = sx >> 1;
    const int ty_lo = ((sy & 1) == 0 && ty_hi > 0) ? ty_hi - 1 : ty_hi;
    const int tx_lo = ((sx & 1) == 0 && tx_hi > 0) ? tx_hi - 1 : tx_hi;

    for (int ty = ty_lo; ty <= ty_hi; ++ty) {
        const int cb0 = (b * CBY + ty) * CBX + tx_lo;
        const int cb1 = (b * CBY + ty) * CBX + tx_hi;
        const unsigned start = offs[cb0];
        const unsigned end   = offs[cb1 + 1];   // x-adjacent buckets contiguous
        for (unsigned i = start + tid; i < end; i += 256) {
            const float4 r = recs[i];
            const float wy = r.x, wx = r.y, nts = r.z;
            const int p = (int)(__float_as_uint(r.w) & 1u);
            const float byf = floorf(wy), bxf = floorf(wx);
            const int iy0 = (int)byf, ix0 = (int)bxf;
            const float ay = wy - byf, ax = wx - bxf;
            const float wyv[2] = {1.0f - ay, ay};
            const float wxv[2] = {1.0f - ax, ax};
            float* accc = acc + (p ? 0 : 1) * ACC_PLANE;  // count plane
            float* acct = accc + 2 * ACC_PLANE;           // ts plane
            #pragma unroll
            for (int dy = 0; dy < 2; ++dy) {
                const int gy = iy0 + dy;
                if ((gy >> 4) != sy) continue;            // also rejects gy<0 / >=H
                #pragma unroll
                for (int dx = 0; dx < 2; ++dx) {
                    const int gx = ix0 + dx;
                    if ((gx >> 5) != sx) continue;        // also rejects gx<0 / >=W
                    const float w = wyv[dy] * wxv[dx];
                    const int idx = (gy & (OT_H - 1)) * OT_W + (gx & (OT_W - 1));
                    atomicAdd(&accc[idx], w);
                    atomicAdd(&acct[idx], w * nts);
                }
            }
        }
    }
    __syncthreads();

    // writeout: 512 float4 chunks over 256 threads (2 each), all plain stores
    const int y0 = sy * OT_H;
    const int x0 = sx * OT_W;
    const float4* acc4 = (const float4*)acc;
    float* outb = out + (size_t)b * 4 * IMG_H * IMG_W;
    #pragma unroll
    for (int q = tid; q < ACC_TOT / 4; q += 256) {
        const int plane = q / (ACC_PLANE / 4);
        const int rem   = q % (ACC_PLANE / 4);
        const int ry    = rem / (OT_W / 4);
        const int rx4   = rem % (OT_W / 4);
        float4* dst = (float4*)(outb + (size_t)plane * IMG_H * IMG_W
                                + (size_t)(y0 + ry) * IMG_W + x0 + rx4 * 4);
        *dst = acc4[q];
    }
}

// ---------------------------------------------------------------------------
// Fallback: direct global atomics (needs zeroed out).
__global__ void __launch_bounds__(256)
event_splat_fallback(const float* __restrict__ flow, const float* __restrict__ ts,
                     const int* __restrict__ ev_y, const int* __restrict__ ev_x,
                     const int* __restrict__ pol, float* __restrict__ out,
                     int N, int total) {
    const int i = blockIdx.x * blockDim.x + threadIdx.x;
    if (i >= total) return;
    float wy, wx, nts; int p;
    unsigned tile = compute_tile(flow, ts, ev_y, ev_x, pol, i, N, wy, wx, nts, p);
    if (tile == SENTINEL) return;
    const int b = i / N;
    const float byf = floorf(wy), bxf = floorf(wx);
    const int iy0 = (int)byf, ix0 = (int)bxf;
    const float ay = wy - byf, ax = wx - bxf;
    const float wyv[2] = {1.0f - ay, ay};
    const float wxv[2] = {1.0f - ax, ax};
    float* out_c = out + ((size_t)b * 4 + (p ? 0 : 1)) * IMG_H * IMG_W;
    float* out_t = out_c + 2 * IMG_H * IMG_W;
    #pragma unroll
    for (int dy = 0; dy < 2; ++dy) {
        const int gy = iy0 + dy;
        if (gy < 0 || gy >= IMG_H) continue;
        #pragma unroll
        for (int dx = 0; dx < 2; ++dx) {
            const int gx = ix0 + dx;
            if (gx < 0 || gx >= IMG_W) continue;
            const float w = wyv[dy] * wxv[dx];
            const int o = gy * IMG_W + gx;
            atomicAdd(out_c + o, w);
            atomicAdd(out_t + o, w * nts);
        }
    }
}

// ---------------------------------------------------------------------------
extern "C" void kernel_launch(void* const* d_in, const int* in_sizes, int n_in,
                              void* d_out, int out_size, void* d_ws, size_t ws_size,
                              hipStream_t stream) {
    const float* flow = (const float*)d_in[0];
    const float* ts   = (const float*)d_in[1];
    const int*   ev_y = (const int*)d_in[2];
    const int*   ev_x = (const int*)d_in[3];
    const int*   pol  = (const int*)d_in[4];
    float* out = (float*)d_out;

    const int total = in_sizes[2];                  // B*N
    const int B = out_size / (4 * IMG_H * IMG_W);
    const int N = total / B;

    const size_t ws_needed = (size_t)WS_RECS + (size_t)total * sizeof(float4);
    if (B * CB_PER_B != NCB || ws_size < ws_needed) {
        hipMemsetAsync(d_out, 0, (size_t)out_size * sizeof(float), stream);
        const int blocks = (total + 255) / 256;
        event_splat_fallback<<<blocks, 256, 0, stream>>>(flow, ts, ev_y, ev_x, pol,
                                                         out, N, total);
        return;
    }

    char* ws = (char*)d_ws;
    unsigned* hist = (unsigned*)(ws + WS_HIST);
    unsigned* offs = (unsigned*)(ws + WS_OFFS);
    unsigned* curs = (unsigned*)(ws + WS_CURS);
    float4*   recs = (float4*)(ws + WS_RECS);

    hipMemsetAsync(hist, 0, NCB * sizeof(unsigned), stream);

    hist_kernel<<<300, 256, 0, stream>>>(flow, ts, ev_y, ev_x, pol, hist, N, total);
    scan_kernel<<<1, 1024, 0, stream>>>(hist, offs, curs);
    const int sc_blocks = (total + SC_CHUNK - 1) / SC_CHUNK;
    scatter_kernel<<<sc_blocks, 256, 0, stream>>>(flow, ts, ev_y, ev_x, pol,
                                                  curs, recs, N, total);
    // B*600 ownership-tile blocks; out-memset not needed (every cell stored)
    splat_kernel<<<B * OT_PER_B, 256, 0, stream>>>(recs, offs, out);
}